// Round 1
// baseline (304.802 us; speedup 1.0000x reference)
//
#include <hip/hip_runtime.h>
#include <hip/hip_bf16.h>

#define C_ 256
#define H_ 8
#define DH_ 32
#define L_ 1024

__device__ __forceinline__ float bflo(unsigned u) { return __uint_as_float(u << 16); }
__device__ __forceinline__ float bfhi(unsigned u) { return __uint_as_float(u & 0xffff0000u); }
__device__ __forceinline__ unsigned short f2bf(float f) {
    unsigned u = __float_as_uint(f);
    u += 0x7fffu + ((u >> 16) & 1u);
    return (unsigned short)(u >> 16);
}

#define GET4(v, kk) ((kk) == 0 ? (v).x : (kk) == 1 ? (v).y : (kk) == 2 ? (v).z : (v).w)

// ---------------- K0: transpose four 256x256 weight matrices into ws ----------------
__global__ void transpose_w(const float* __restrict__ Wq, const float* __restrict__ Wk,
                            const float* __restrict__ Wv, const float* __restrict__ Wo,
                            float* __restrict__ WqT, float* __restrict__ WkT,
                            float* __restrict__ WvT, float* __restrict__ WoT)
{
    const float* src = (blockIdx.y == 0) ? Wq : (blockIdx.y == 1) ? Wk : (blockIdx.y == 2) ? Wv : Wo;
    float* dst       = (blockIdx.y == 0) ? WqT : (blockIdx.y == 1) ? WkT : (blockIdx.y == 2) ? WvT : WoT;
    __shared__ float tile[32][33];
    int c0 = blockIdx.x * 32;
    int t = threadIdx.x;
    for (int k0 = 0; k0 < 256; k0 += 32) {
#pragma unroll
        for (int p = 0; p < 4; ++p) {
            int cc = (t >> 5) + p * 8;
            int kk = t & 31;
            tile[cc][kk] = src[(c0 + cc) * 256 + k0 + kk];
        }
        __syncthreads();
#pragma unroll
        for (int p = 0; p < 4; ++p) {
            int kk = (t >> 5) + p * 8;
            int cc = t & 31;
            dst[(k0 + kk) * 256 + c0 + cc] = tile[cc][kk];
        }
        __syncthreads();
    }
}

// ---------------- K1: QKV projection -> bf16, head-split, q pre-scaled ----------------
// grid (512, 3), block 256. Block = 16 rows x 256 cols of one matrix.
__global__ __launch_bounds__(256) void qkv_proj(
    const float* __restrict__ x,
    const float* __restrict__ WqT, const float* __restrict__ WkT, const float* __restrict__ WvT,
    const float* __restrict__ bq, const float* __restrict__ bk, const float* __restrict__ bv,
    unsigned short* __restrict__ qws, unsigned short* __restrict__ kws, unsigned short* __restrict__ vws)
{
    int z = blockIdx.y;
    const float* WT   = (z == 0) ? WqT : (z == 1) ? WkT : WvT;
    const float* bias = (z == 0) ? bq  : (z == 1) ? bk  : bv;
    unsigned short* dst = (z == 0) ? qws : (z == 1) ? kws : vws;
    int row0 = blockIdx.x * 16;
    int t = threadIdx.x;
    __shared__ float xl[16][256];
#pragma unroll
    for (int r = 0; r < 16; ++r)
        xl[r][t] = x[(size_t)(row0 + r) * 256 + t];
    __syncthreads();

    int cg = t & 63, rg = t >> 6;
    float4 b4 = *(const float4*)&bias[cg * 4];
    float4 acc[4];
#pragma unroll
    for (int i = 0; i < 4; ++i) acc[i] = b4;

    for (int k4 = 0; k4 < 64; ++k4) {
        float4 a0 = *(const float4*)&xl[rg * 4 + 0][k4 * 4];
        float4 a1 = *(const float4*)&xl[rg * 4 + 1][k4 * 4];
        float4 a2 = *(const float4*)&xl[rg * 4 + 2][k4 * 4];
        float4 a3 = *(const float4*)&xl[rg * 4 + 3][k4 * 4];
        const float* wp = &WT[(k4 * 4) * 256 + cg * 4];
#pragma unroll
        for (int kk = 0; kk < 4; ++kk) {
            float4 w = *(const float4*)&wp[kk * 256];
            float e0 = GET4(a0, kk), e1 = GET4(a1, kk), e2 = GET4(a2, kk), e3 = GET4(a3, kk);
            acc[0].x += e0 * w.x; acc[0].y += e0 * w.y; acc[0].z += e0 * w.z; acc[0].w += e0 * w.w;
            acc[1].x += e1 * w.x; acc[1].y += e1 * w.y; acc[1].z += e1 * w.z; acc[1].w += e1 * w.w;
            acc[2].x += e2 * w.x; acc[2].y += e2 * w.y; acc[2].z += e2 * w.z; acc[2].w += e2 * w.w;
            acc[3].x += e3 * w.x; acc[3].y += e3 * w.y; acc[3].z += e3 * w.z; acc[3].w += e3 * w.w;
        }
    }

    const float qscale = 0.17677669529663687f; // 1/sqrt(32), folded into q (incl. bias, matching ref)
    float s = (z == 0) ? qscale : 1.0f;
    int h = cg >> 3, d0 = (cg & 7) * 4;
#pragma unroll
    for (int i = 0; i < 4; ++i) {
        int row = row0 + rg * 4 + i;
        int bs = row >> 10, l = row & 1023;
        ushort4 o;
        o.x = f2bf(acc[i].x * s); o.y = f2bf(acc[i].y * s);
        o.z = f2bf(acc[i].z * s); o.w = f2bf(acc[i].w * s);
        *(ushort4*)&dst[((size_t)((bs * H_ + h) * L_ + l)) * DH_ + d0] = o;
    }
}

// ---------------- K2: attention (bias + softmax + PV), K/V LDS-resident ----------------
// grid (16, 64): x = 64-row tile, y = head (bs*8+h). block 512 = 8 waves, 8 rows/wave.
__global__ __launch_bounds__(512) void attn_k(
    const unsigned short* __restrict__ qws, const unsigned short* __restrict__ kws,
    const unsigned short* __restrict__ vws, const float* __restrict__ bulk,
    const float* __restrict__ conv_w, const float* __restrict__ conv_b,
    float* __restrict__ og)
{
    __shared__ unsigned Kt[16 * 1024]; // [d2][j ^ (d2<<2)] : bf16 pair (d=2*d2, 2*d2+1)
    __shared__ unsigned Vt[16 * 1024];
    int hb = blockIdx.y;
    int h = hb & 7;
    int bs = hb >> 3;
    int b = bs >> 2; // bs / S
    int r0 = blockIdx.x * 64;
    int tid = threadIdx.x;

    const unsigned* kg = (const unsigned*)kws + (size_t)hb * 16384;
    const unsigned* vg = (const unsigned*)vws + (size_t)hb * 16384;
    for (int i = tid; i < 16384; i += 512) {
        int j = i >> 4, d2 = i & 15;
        int a = (d2 << 10) + (j ^ (d2 << 2)); // bank-conflict-free store & load
        Kt[a] = kg[i];
        Vt[a] = vg[i];
    }
    __syncthreads();

    int wave = tid >> 6, lane = tid & 63;
    float cw = conv_w[h], cb = conv_b[h];
    const unsigned* qg = (const unsigned*)qws + (size_t)hb * 16384;

    for (int g = 0; g < 2; ++g) {
        int i0 = r0 + wave * 8 + g * 4; // 4 rows per group
        unsigned myq = qg[(i0 + (lane >> 4)) * 16 + (lane & 15)];
        float s[4][16];
        // ---- bias init from bulk map ----
#pragma unroll
        for (int r = 0; r < 4; ++r) {
            const float* bp = &bulk[((size_t)(b * 1024 + i0 + r) << 10) + lane];
#pragma unroll
            for (int t = 0; t < 16; ++t)
                s[r][t] = cw * bp[t << 6] + cb;
        }
        // ---- scores: q . k (q pre-scaled) ----
        for (int d2 = 0; d2 < 16; ++d2) {
            float q0[4], q1[4];
#pragma unroll
            for (int r = 0; r < 4; ++r) {
                unsigned qq = __shfl(myq, (r << 4) | d2, 64);
                q0[r] = bflo(qq); q1[r] = bfhi(qq);
            }
            const unsigned* Kp = &Kt[(d2 << 10) + (lane ^ (d2 << 2))];
#pragma unroll
            for (int t = 0; t < 16; ++t) {
                unsigned kk = Kp[t << 6];
                float k0 = bflo(kk), k1 = bfhi(kk);
#pragma unroll
                for (int r = 0; r < 4; ++r)
                    s[r][t] += q0[r] * k0 + q1[r] * k1;
            }
        }
        // ---- softmax ----
        float linv[4];
#pragma unroll
        for (int r = 0; r < 4; ++r) {
            float m = s[r][0];
#pragma unroll
            for (int t = 1; t < 16; ++t) m = fmaxf(m, s[r][t]);
            m = fmaxf(m, __shfl_xor(m, 32, 64));
            m = fmaxf(m, __shfl_xor(m, 16, 64));
            m = fmaxf(m, __shfl_xor(m, 8, 64));
            m = fmaxf(m, __shfl_xor(m, 4, 64));
            m = fmaxf(m, __shfl_xor(m, 2, 64));
            m = fmaxf(m, __shfl_xor(m, 1, 64));
            float l = 0.f;
#pragma unroll
            for (int t = 0; t < 16; ++t) { float p = __expf(s[r][t] - m); s[r][t] = p; l += p; }
            l += __shfl_xor(l, 32, 64);
            l += __shfl_xor(l, 16, 64);
            l += __shfl_xor(l, 8, 64);
            l += __shfl_xor(l, 4, 64);
            l += __shfl_xor(l, 2, 64);
            l += __shfl_xor(l, 1, 64);
            linv[r] = 1.0f / l;
        }
        // ---- PV + descending butterfly reduce ----
        for (int d2 = 0; d2 < 16; ++d2) {
            float a0[4] = {0.f, 0.f, 0.f, 0.f}, a1[4] = {0.f, 0.f, 0.f, 0.f};
            const unsigned* Vp = &Vt[(d2 << 10) + (lane ^ (d2 << 2))];
#pragma unroll
            for (int t = 0; t < 16; ++t) {
                unsigned vv = Vp[t << 6];
                float v0 = bflo(vv), v1 = bfhi(vv);
#pragma unroll
                for (int r = 0; r < 4; ++r) { a0[r] += s[r][t] * v0; a1[r] += s[r][t] * v1; }
            }
            bool bit0 = lane & 1, bit1 = lane & 2, bit2 = lane & 4;
            float v4[4];
#pragma unroll
            for (int r = 0; r < 4; ++r) {
                float keep = bit0 ? a1[r] : a0[r];
                float send = bit0 ? a0[r] : a1[r];
                v4[r] = keep + __shfl_xor(send, 1, 64);
            }
            float v2[2];
#pragma unroll
            for (int i = 0; i < 2; ++i) {
                float keep = bit1 ? v4[2 + i] : v4[i];
                float send = bit1 ? v4[i] : v4[2 + i];
                v2[i] = keep + __shfl_xor(send, 2, 64);
            }
            float keep = bit2 ? v2[1] : v2[0];
            float send = bit2 ? v2[0] : v2[1];
            float v1 = keep + __shfl_xor(send, 4, 64);
            v1 += __shfl_xor(v1, 8, 64);
            v1 += __shfl_xor(v1, 16, 64);
            v1 += __shfl_xor(v1, 32, 64);
            if (lane < 8) {
                int rr = ((lane >> 1) & 1) * 2 + ((lane >> 2) & 1);
                int e = lane & 1;
                float li = (rr == 0) ? linv[0] : (rr == 1) ? linv[1] : (rr == 2) ? linv[2] : linv[3];
                og[((size_t)hb * 1024 + i0 + rr) * 32 + (d2 << 1) + e] = v1 * li;
            }
        }
    }
}

// ---------------- K3: gate + out-proj + residual + layernorm ----------------
// grid 512, block 256. Block = 16 rows.
__global__ __launch_bounds__(256) void gate_proj_ln(
    const float* __restrict__ og, const float* __restrict__ x,
    const float* __restrict__ WoT, const float* __restrict__ bo,
    const float* __restrict__ gate_w, const float* __restrict__ gate_b,
    const float* __restrict__ ln_g, const float* __restrict__ ln_b,
    float* __restrict__ out)
{
    int row0 = blockIdx.x * 16;
    int bs = row0 >> 10, l0 = row0 & 1023;
    int t = threadIdx.x;
    __shared__ float ol[16][256];
    __shared__ float gl[16][256];
    int h = t >> 5, dd = t & 31;
    const float* obase = og + ((size_t)(bs * 8 + h) * 1024 + l0) * 32 + dd;
#pragma unroll
    for (int r = 0; r < 16; ++r)
        ol[r][t] = obase[r * 32];
    __syncthreads();

    float gw[32];
#pragma unroll
    for (int d = 0; d < 32; ++d) gw[d] = gate_w[(h * 32 + dd) * 32 + d];
    float gb = gate_b[h * 32 + dd];
#pragma unroll
    for (int r = 0; r < 16; ++r) {
        float a = gb;
#pragma unroll
        for (int d = 0; d < 32; ++d) a += gw[d] * ol[r][(h << 5) + d];
        float gate = 1.0f / (1.0f + __expf(-a));
        gl[r][t] = ol[r][t] * gate;
    }
    __syncthreads();

    int cg = t & 63, rg = t >> 6;
    float4 b4 = *(const float4*)&bo[cg * 4];
    float4 acc[4];
#pragma unroll
    for (int i = 0; i < 4; ++i) acc[i] = b4;

    for (int k4 = 0; k4 < 64; ++k4) {
        float4 a0 = *(const float4*)&gl[rg * 4 + 0][k4 * 4];
        float4 a1 = *(const float4*)&gl[rg * 4 + 1][k4 * 4];
        float4 a2 = *(const float4*)&gl[rg * 4 + 2][k4 * 4];
        float4 a3 = *(const float4*)&gl[rg * 4 + 3][k4 * 4];
        const float* wp = &WoT[(k4 * 4) * 256 + cg * 4];
#pragma unroll
        for (int kk = 0; kk < 4; ++kk) {
            float4 w = *(const float4*)&wp[kk * 256];
            float e0 = GET4(a0, kk), e1 = GET4(a1, kk), e2 = GET4(a2, kk), e3 = GET4(a3, kk);
            acc[0].x += e0 * w.x; acc[0].y += e0 * w.y; acc[0].z += e0 * w.z; acc[0].w += e0 * w.w;
            acc[1].x += e1 * w.x; acc[1].y += e1 * w.y; acc[1].z += e1 * w.z; acc[1].w += e1 * w.w;
            acc[2].x += e2 * w.x; acc[2].y += e2 * w.y; acc[2].z += e2 * w.z; acc[2].w += e2 * w.w;
            acc[3].x += e3 * w.x; acc[3].y += e3 * w.y; acc[3].z += e3 * w.z; acc[3].w += e3 * w.w;
        }
    }

    float4 g4  = *(const float4*)&ln_g[cg * 4];
    float4 bb4 = *(const float4*)&ln_b[cg * 4];
#pragma unroll
    for (int i = 0; i < 4; ++i) {
        int row = row0 + rg * 4 + i;
        float4 xv = *(const float4*)&x[(size_t)row * 256 + cg * 4];
        float4 yv;
        yv.x = acc[i].x + xv.x; yv.y = acc[i].y + xv.y;
        yv.z = acc[i].z + xv.z; yv.w = acc[i].w + xv.w;
        float sm = yv.x + yv.y + yv.z + yv.w;
        float sq = yv.x * yv.x + yv.y * yv.y + yv.z * yv.z + yv.w * yv.w;
        sm += __shfl_xor(sm, 32, 64); sq += __shfl_xor(sq, 32, 64);
        sm += __shfl_xor(sm, 16, 64); sq += __shfl_xor(sq, 16, 64);
        sm += __shfl_xor(sm, 8, 64);  sq += __shfl_xor(sq, 8, 64);
        sm += __shfl_xor(sm, 4, 64);  sq += __shfl_xor(sq, 4, 64);
        sm += __shfl_xor(sm, 2, 64);  sq += __shfl_xor(sq, 2, 64);
        sm += __shfl_xor(sm, 1, 64);  sq += __shfl_xor(sq, 1, 64);
        float mu = sm * (1.0f / 256.0f);
        float var = sq * (1.0f / 256.0f) - mu * mu;
        float rs = rsqrtf(var + 1e-5f);
        float4 o4;
        o4.x = (yv.x - mu) * rs * g4.x + bb4.x;
        o4.y = (yv.y - mu) * rs * g4.y + bb4.y;
        o4.z = (yv.z - mu) * rs * g4.z + bb4.z;
        o4.w = (yv.w - mu) * rs * g4.w + bb4.w;
        *(float4*)&out[(size_t)row * 256 + cg * 4] = o4;
    }
}

extern "C" void kernel_launch(void* const* d_in, const int* in_sizes, int n_in,
                              void* d_out, int out_size, void* d_ws, size_t ws_size,
                              hipStream_t stream)
{
    (void)in_sizes; (void)n_in; (void)out_size; (void)ws_size;
    const float* x      = (const float*)d_in[0];
    const float* bulk   = (const float*)d_in[1];
    const float* Wq     = (const float*)d_in[2];
    const float* bq     = (const float*)d_in[3];
    const float* Wk     = (const float*)d_in[4];
    const float* bk     = (const float*)d_in[5];
    const float* Wv     = (const float*)d_in[6];
    const float* bv     = (const float*)d_in[7];
    const float* Wo     = (const float*)d_in[8];
    const float* bo     = (const float*)d_in[9];
    const float* conv_w = (const float*)d_in[10];
    const float* conv_b = (const float*)d_in[11];
    const float* gate_w = (const float*)d_in[12];
    const float* gate_b = (const float*)d_in[13];
    const float* ln_g   = (const float*)d_in[14];
    const float* ln_b   = (const float*)d_in[15];
    float* out = (float*)d_out;

    char* ws = (char*)d_ws;
    float* WqT = (float*)ws;            // 256 KB
    float* WkT = WqT + 65536;           // 256 KB
    float* WvT = WqT + 131072;          // 256 KB
    float* WoT = WqT + 196608;          // 256 KB  (ends at 1 MB)
    unsigned short* qws = (unsigned short*)(ws + (1u << 20));   // 4 MB bf16
    unsigned short* kws = qws + 2097152;                        // 4 MB
    unsigned short* vws = qws + 4194304;                        // 4 MB
    float* og = (float*)(ws + (1u << 20) + 3u * (1u << 22));    // 8 MB f32 (total 21 MB)

    transpose_w<<<dim3(8, 4), 256, 0, stream>>>(Wq, Wk, Wv, Wo, WqT, WkT, WvT, WoT);
    qkv_proj<<<dim3(512, 3), 256, 0, stream>>>(x, WqT, WkT, WvT, bq, bk, bv, qws, kws, vws);
    attn_k<<<dim3(16, 64), 512, 0, stream>>>(qws, kws, vws, bulk, conv_w, conv_b, og);
    gate_proj_ln<<<512, 256, 0, stream>>>(og, x, WoT, bo, gate_w, gate_b, ln_g, ln_b, out);
}

// Round 2
// 155.028 us; speedup vs baseline: 1.9661x; 1.9661x over previous
//
#include <hip/hip_runtime.h>
#include <hip/hip_bf16.h>

#define C_ 256
#define H_ 8
#define DH_ 32
#define L_ 1024

typedef __bf16 bf16x8_t __attribute__((ext_vector_type(8)));
typedef float f32x4_t __attribute__((ext_vector_type(4)));

union V16 {
    uint4 u4;
    bf16x8_t b8;
    f32x4_t f4;
    unsigned u[4];
};

__device__ __forceinline__ unsigned cvt_pk(float lo, float hi) {
    unsigned r;
    asm volatile("v_cvt_pk_bf16_f32 %0, %1, %2" : "=v"(r) : "v"(lo), "v"(hi));
    return r;
}

__device__ __forceinline__ f32x4_t mfma16(bf16x8_t a, bf16x8_t b, f32x4_t c) {
    return __builtin_amdgcn_mfma_f32_16x16x32_bf16(a, b, c, 0, 0, 0);
}

__device__ __forceinline__ unsigned short f2bf(float f) {
    unsigned u = __float_as_uint(f);
    u += 0x7fffu + ((u >> 16) & 1u);
    return (unsigned short)(u >> 16);
}

#define GET4(v, kk) ((kk) == 0 ? (v).x : (kk) == 1 ? (v).y : (kk) == 2 ? (v).z : (v).w)

// ---------------- K0: transpose four 256x256 weight matrices into ws ----------------
__global__ void transpose_w(const float* __restrict__ Wq, const float* __restrict__ Wk,
                            const float* __restrict__ Wv, const float* __restrict__ Wo,
                            float* __restrict__ WqT, float* __restrict__ WkT,
                            float* __restrict__ WvT, float* __restrict__ WoT)
{
    const float* src = (blockIdx.y == 0) ? Wq : (blockIdx.y == 1) ? Wk : (blockIdx.y == 2) ? Wv : Wo;
    float* dst       = (blockIdx.y == 0) ? WqT : (blockIdx.y == 1) ? WkT : (blockIdx.y == 2) ? WvT : WoT;
    __shared__ float tile[32][33];
    int c0 = blockIdx.x * 32;
    int t = threadIdx.x;
    for (int k0 = 0; k0 < 256; k0 += 32) {
#pragma unroll
        for (int p = 0; p < 4; ++p) {
            int cc = (t >> 5) + p * 8;
            int kk = t & 31;
            tile[cc][kk] = src[(c0 + cc) * 256 + k0 + kk];
        }
        __syncthreads();
#pragma unroll
        for (int p = 0; p < 4; ++p) {
            int kk = (t >> 5) + p * 8;
            int cc = t & 31;
            dst[(k0 + kk) * 256 + c0 + cc] = tile[cc][kk];
        }
        __syncthreads();
    }
}

// ---------------- K1: QKV projection -> bf16, head-split, q pre-scaled ----------------
// grid (512, 3), block 256. Block = 16 rows x 256 cols of one matrix.
__global__ __launch_bounds__(256) void qkv_proj(
    const float* __restrict__ x,
    const float* __restrict__ WqT, const float* __restrict__ WkT, const float* __restrict__ WvT,
    const float* __restrict__ bq, const float* __restrict__ bk, const float* __restrict__ bv,
    unsigned short* __restrict__ qws, unsigned short* __restrict__ kws, unsigned short* __restrict__ vws)
{
    int z = blockIdx.y;
    const float* WT   = (z == 0) ? WqT : (z == 1) ? WkT : WvT;
    const float* bias = (z == 0) ? bq  : (z == 1) ? bk  : bv;
    unsigned short* dst = (z == 0) ? qws : (z == 1) ? kws : vws;
    int row0 = blockIdx.x * 16;
    int t = threadIdx.x;
    __shared__ float xl[16][256];
#pragma unroll
    for (int r = 0; r < 16; ++r)
        xl[r][t] = x[(size_t)(row0 + r) * 256 + t];
    __syncthreads();

    int cg = t & 63, rg = t >> 6;
    float4 b4 = *(const float4*)&bias[cg * 4];
    float4 acc[4];
#pragma unroll
    for (int i = 0; i < 4; ++i) acc[i] = b4;

    for (int k4 = 0; k4 < 64; ++k4) {
        float4 a0 = *(const float4*)&xl[rg * 4 + 0][k4 * 4];
        float4 a1 = *(const float4*)&xl[rg * 4 + 1][k4 * 4];
        float4 a2 = *(const float4*)&xl[rg * 4 + 2][k4 * 4];
        float4 a3 = *(const float4*)&xl[rg * 4 + 3][k4 * 4];
        const float* wp = &WT[(k4 * 4) * 256 + cg * 4];
#pragma unroll
        for (int kk = 0; kk < 4; ++kk) {
            float4 w = *(const float4*)&wp[kk * 256];
            float e0 = GET4(a0, kk), e1 = GET4(a1, kk), e2 = GET4(a2, kk), e3 = GET4(a3, kk);
            acc[0].x += e0 * w.x; acc[0].y += e0 * w.y; acc[0].z += e0 * w.z; acc[0].w += e0 * w.w;
            acc[1].x += e1 * w.x; acc[1].y += e1 * w.y; acc[1].z += e1 * w.z; acc[1].w += e1 * w.w;
            acc[2].x += e2 * w.x; acc[2].y += e2 * w.y; acc[2].z += e2 * w.z; acc[2].w += e2 * w.w;
            acc[3].x += e3 * w.x; acc[3].y += e3 * w.y; acc[3].z += e3 * w.z; acc[3].w += e3 * w.w;
        }
    }

    const float qscale = 0.17677669529663687f; // 1/sqrt(32)
    float s = (z == 0) ? qscale : 1.0f;
    int h = cg >> 3, d0 = (cg & 7) * 4;
#pragma unroll
    for (int i = 0; i < 4; ++i) {
        int row = row0 + rg * 4 + i;
        int bs = row >> 10, l = row & 1023;
        ushort4 o;
        o.x = f2bf(acc[i].x * s); o.y = f2bf(acc[i].y * s);
        o.z = f2bf(acc[i].z * s); o.w = f2bf(acc[i].w * s);
        *(ushort4*)&dst[((size_t)((bs * H_ + h) * L_ + l)) * DH_ + d0] = o;
    }
}

// ---------------- K1b: transpose V per head: [hb][l][d] -> [hb][d][l] ----------------
// grid (4, 64), block 256. 256 l x 32 d per block.
__global__ __launch_bounds__(256) void transpose_v(const unsigned short* __restrict__ vws,
                                                   unsigned short* __restrict__ vT)
{
    __shared__ unsigned short tile[32][264];
    int hb = blockIdx.y;
    int l0 = blockIdx.x * 256;
    int t = threadIdx.x;
    const unsigned* src = (const unsigned*)(vws + (size_t)hb * 32768) + l0 * 16;
    for (int i = t; i < 4096; i += 256) {
        int l = i >> 4, d2 = i & 15;
        unsigned u = src[i];
        tile[d2 * 2][l]     = (unsigned short)(u & 0xffffu);
        tile[d2 * 2 + 1][l] = (unsigned short)(u >> 16);
    }
    __syncthreads();
    unsigned* dst = (unsigned*)(vT + (size_t)hb * 32768);
    int d = t >> 3, seg = (t & 7) * 32;
#pragma unroll
    for (int j = 0; j < 16; ++j) {
        int l = seg + j * 2;
        unsigned u = (unsigned)tile[d][l] | ((unsigned)tile[d][l + 1] << 16);
        dst[d * 512 + (l0 + l) / 2] = u;
    }
}

// ---------------- K2: MFMA flash attention + fused gate ----------------
// grid (16, 16): x = 64-q tile, y = b*8+h. block 512 = 8 waves = 4 tracks x 2 q-halves.
// Swapped QK^T: S^T = mfma(K, Q^T) so D col = q. PV: O^T = mfma(V^T, P^T).
__global__ __launch_bounds__(512, 2) void attn_mfma(
    const unsigned short* __restrict__ qws, const unsigned short* __restrict__ kws,
    const unsigned short* __restrict__ vT, const float* __restrict__ bulk,
    const float* __restrict__ conv_w, const float* __restrict__ conv_b,
    const float* __restrict__ gate_w, const float* __restrict__ gate_b,
    float* __restrict__ og)
{
    const int t = threadIdx.x;
    const int lane = t & 63, w = t >> 6;
    const int g = lane >> 4, r = lane & 15;
    const int s = w & 3, qh = w >> 2;
    const int h = blockIdx.y & 7, b = blockIdx.y >> 3;
    const int hb = (b * 4 + s) * 8 + h;
    const int q0 = blockIdx.x * 64 + qh * 32;

    const uint4* kp = (const uint4*)(kws + (size_t)hb * 32768);
    const uint4* qp = (const uint4*)(qws + (size_t)hb * 32768);
    const uint4* vp = (const uint4*)(vT  + (size_t)hb * 32768);
    const float* bulkp = bulk + (size_t)b * 1048576;
    const float cw = conv_w[h], cb = conv_b[h];

    // Q B-frags: lane holds Q[q0+n*16+r][g*8 .. g*8+7]
    bf16x8_t qb[2];
#pragma unroll
    for (int n = 0; n < 2; ++n) {
        V16 tmp; tmp.u4 = qp[(q0 + n * 16 + r) * 4 + g];
        qb[n] = tmp.b8;
    }
    // gate_w A-frags (c = mc*16+r rows, d = g*8.. cols) + gate_b (c = mc*16+g*4+reg)
    bf16x8_t ga[2]; f32x4_t gb4[2];
#pragma unroll
    for (int mc = 0; mc < 2; ++mc) {
        const float* gwp = gate_w + (size_t)(h * 32 + mc * 16 + r) * 32 + g * 8;
        f32x4_t w0 = *(const f32x4_t*)gwp;
        f32x4_t w1 = *(const f32x4_t*)(gwp + 4);
        V16 tmp;
        tmp.u[0] = cvt_pk(w0[0], w0[1]); tmp.u[1] = cvt_pk(w0[2], w0[3]);
        tmp.u[2] = cvt_pk(w1[0], w1[1]); tmp.u[3] = cvt_pk(w1[2], w1[3]);
        ga[mc] = tmp.b8;
        gb4[mc] = *(const f32x4_t*)(gate_b + h * 32 + mc * 16 + g * 4);
    }

    f32x4_t o[2][2] = {};           // [d-frag][q-frag], D: col=q=r, row=d=md*16+g*4+reg
    float mst[2] = {-1e30f, -1e30f};
    float lst[2] = {0.f, 0.f};

    for (int kt = 0; kt < 16; ++kt) {
        const int kv0 = kt * 64;
        // K A-frags: K[kv0+m*16+r][g*8..]
        bf16x8_t ka[4];
#pragma unroll
        for (int m = 0; m < 4; ++m) {
            V16 tmp; tmp.u4 = kp[(kv0 + m * 16 + r) * 4 + g];
            ka[m] = tmp.b8;
        }
        // V^T A-frags: vT[md*16+r][kv0+s2*32+g*8..]
        uint4 vau[4];
#pragma unroll
        for (int md = 0; md < 2; ++md)
#pragma unroll
            for (int s2 = 0; s2 < 2; ++s2)
                vau[md * 2 + s2] = vp[(md * 16 + r) * 128 + (kv0 >> 3) + s2 * 4 + g];

        // S^T tile, bias-initialized: S[kv=m*16+g*4+reg][q=n*16+r]
        f32x4_t acc[4][2];
#pragma unroll
        for (int m = 0; m < 4; ++m)
#pragma unroll
            for (int n = 0; n < 2; ++n) {
                f32x4_t bb = *(const f32x4_t*)(bulkp + (size_t)(q0 + n * 16 + r) * 1024 + kv0 + m * 16 + g * 4);
                acc[m][n] = cw * bb + cb;
            }
#pragma unroll
        for (int m = 0; m < 4; ++m)
#pragma unroll
            for (int n = 0; n < 2; ++n)
                acc[m][n] = mfma16(ka[m], qb[n], acc[m][n]);

#pragma unroll
        for (int n = 0; n < 2; ++n) {
            // --- online softmax over kv for each q = n*16+r ---
            float pmax = acc[0][n][0];
#pragma unroll
            for (int m = 0; m < 4; ++m)
#pragma unroll
                for (int e = 0; e < 4; ++e) pmax = fmaxf(pmax, acc[m][n][e]);
            pmax = fmaxf(pmax, __shfl_xor(pmax, 16, 64));
            pmax = fmaxf(pmax, __shfl_xor(pmax, 32, 64));
            float mnew = fmaxf(mst[n], pmax);
            float scale = __expf(mst[n] - mnew);
            mst[n] = mnew;
            float psum = 0.f;
#pragma unroll
            for (int m = 0; m < 4; ++m)
#pragma unroll
                for (int e = 0; e < 4; ++e) {
                    float p = __expf(acc[m][n][e] - mnew);
                    acc[m][n][e] = p;
                    psum += p;
                }
            psum += __shfl_xor(psum, 16, 64);
            psum += __shfl_xor(psum, 32, 64);
            lst[n] = lst[n] * scale + psum;
            o[0][n] *= scale;
            o[1][n] *= scale;

            // --- pack P -> bf16 pairs, redistribute to P^T B-frags, PV MFMA ---
            unsigned pk[4][2];
#pragma unroll
            for (int m = 0; m < 4; ++m) {
                pk[m][0] = cvt_pk(acc[m][n][0], acc[m][n][1]);
                pk[m][1] = cvt_pk(acc[m][n][2], acc[m][n][3]);
            }
#pragma unroll
            for (int s2 = 0; s2 < 2; ++s2) {
                V16 pb;
#pragma unroll
                for (int u = 0; u < 4; ++u) {
                    int srcl = ((2 * (g & 1) + (u >> 1)) << 4) | r;
                    unsigned lo = (unsigned)__shfl((int)pk[2 * s2][u & 1], srcl, 64);
                    unsigned hi = (unsigned)__shfl((int)pk[2 * s2 + 1][u & 1], srcl, 64);
                    pb.u[u] = (g >= 2) ? hi : lo;
                }
                V16 va0; va0.u4 = vau[0 * 2 + s2];
                V16 va1; va1.u4 = vau[1 * 2 + s2];
                o[0][n] = mfma16(va0.b8, pb.b8, o[0][n]);
                o[1][n] = mfma16(va1.b8, pb.b8, o[1][n]);
            }
        }
    }

    // ---- epilogue: normalize, fused gate (G^T = gate_w . O^T), store ----
#pragma unroll
    for (int n = 0; n < 2; ++n) {
        float linv = 1.0f / lst[n];
        o[0][n] *= linv;
        o[1][n] *= linv;

        unsigned pkO[2][2];
#pragma unroll
        for (int md = 0; md < 2; ++md) {
            pkO[md][0] = cvt_pk(o[md][n][0], o[md][n][1]);
            pkO[md][1] = cvt_pk(o[md][n][2], o[md][n][3]);
        }
        V16 ob;
#pragma unroll
        for (int u = 0; u < 4; ++u) {
            int srcl = ((2 * (g & 1) + (u >> 1)) << 4) | r;
            unsigned lo = (unsigned)__shfl((int)pkO[0][u & 1], srcl, 64);
            unsigned hi = (unsigned)__shfl((int)pkO[1][u & 1], srcl, 64);
            ob.u[u] = (g >= 2) ? hi : lo;
        }
        f32x4_t zero = {0.f, 0.f, 0.f, 0.f};
        f32x4_t gacc0 = mfma16(ga[0], ob.b8, zero);
        f32x4_t gacc1 = mfma16(ga[1], ob.b8, zero);
#pragma unroll
        for (int e = 0; e < 4; ++e) {
            float s0 = 1.0f / (1.0f + __expf(-(gacc0[e] + gb4[0][e])));
            float s1 = 1.0f / (1.0f + __expf(-(gacc1[e] + gb4[1][e])));
            o[0][n][e] *= s0;
            o[1][n][e] *= s1;
        }
#pragma unroll
        for (int m = 0; m < 2; ++m)
            *(f32x4_t*)(og + (size_t)(hb * 1024 + q0 + n * 16 + r) * 32 + m * 16 + g * 4) = o[m][n];
    }
}

// ---------------- K3: out-proj + residual + layernorm (gate already applied) ----------------
// grid 512, block 256. Block = 16 rows.
__global__ __launch_bounds__(256) void proj_ln(
    const float* __restrict__ og, const float* __restrict__ x,
    const float* __restrict__ WoT, const float* __restrict__ bo,
    const float* __restrict__ ln_g, const float* __restrict__ ln_b,
    float* __restrict__ out)
{
    int row0 = blockIdx.x * 16;
    int bs = row0 >> 10, l0 = row0 & 1023;
    int t = threadIdx.x;
    __shared__ float ol[16][256];
    int h = t >> 5, dd = t & 31;
    const float* obase = og + ((size_t)(bs * 8 + h) * 1024 + l0) * 32 + dd;
#pragma unroll
    for (int rr = 0; rr < 16; ++rr)
        ol[rr][t] = obase[rr * 32];
    __syncthreads();

    int cg = t & 63, rg = t >> 6;
    float4 b4 = *(const float4*)&bo[cg * 4];
    float4 acc[4];
#pragma unroll
    for (int i = 0; i < 4; ++i) acc[i] = b4;

    for (int k4 = 0; k4 < 64; ++k4) {
        float4 a0 = *(const float4*)&ol[rg * 4 + 0][k4 * 4];
        float4 a1 = *(const float4*)&ol[rg * 4 + 1][k4 * 4];
        float4 a2 = *(const float4*)&ol[rg * 4 + 2][k4 * 4];
        float4 a3 = *(const float4*)&ol[rg * 4 + 3][k4 * 4];
        const float* wp = &WoT[(k4 * 4) * 256 + cg * 4];
#pragma unroll
        for (int kk = 0; kk < 4; ++kk) {
            float4 ww = *(const float4*)&wp[kk * 256];
            float e0 = GET4(a0, kk), e1 = GET4(a1, kk), e2 = GET4(a2, kk), e3 = GET4(a3, kk);
            acc[0].x += e0 * ww.x; acc[0].y += e0 * ww.y; acc[0].z += e0 * ww.z; acc[0].w += e0 * ww.w;
            acc[1].x += e1 * ww.x; acc[1].y += e1 * ww.y; acc[1].z += e1 * ww.z; acc[1].w += e1 * ww.w;
            acc[2].x += e2 * ww.x; acc[2].y += e2 * ww.y; acc[2].z += e2 * ww.z; acc[2].w += e2 * ww.w;
            acc[3].x += e3 * ww.x; acc[3].y += e3 * ww.y; acc[3].z += e3 * ww.z; acc[3].w += e3 * ww.w;
        }
    }

    float4 g4  = *(const float4*)&ln_g[cg * 4];
    float4 bb4 = *(const float4*)&ln_b[cg * 4];
#pragma unroll
    for (int i = 0; i < 4; ++i) {
        int row = row0 + rg * 4 + i;
        float4 xv = *(const float4*)&x[(size_t)row * 256 + cg * 4];
        float4 yv;
        yv.x = acc[i].x + xv.x; yv.y = acc[i].y + xv.y;
        yv.z = acc[i].z + xv.z; yv.w = acc[i].w + xv.w;
        float sm = yv.x + yv.y + yv.z + yv.w;
        float sq = yv.x * yv.x + yv.y * yv.y + yv.z * yv.z + yv.w * yv.w;
        sm += __shfl_xor(sm, 32, 64); sq += __shfl_xor(sq, 32, 64);
        sm += __shfl_xor(sm, 16, 64); sq += __shfl_xor(sq, 16, 64);
        sm += __shfl_xor(sm, 8, 64);  sq += __shfl_xor(sq, 8, 64);
        sm += __shfl_xor(sm, 4, 64);  sq += __shfl_xor(sq, 4, 64);
        sm += __shfl_xor(sm, 2, 64);  sq += __shfl_xor(sq, 2, 64);
        sm += __shfl_xor(sm, 1, 64);  sq += __shfl_xor(sq, 1, 64);
        float mu = sm * (1.0f / 256.0f);
        float var = sq * (1.0f / 256.0f) - mu * mu;
        float rs = rsqrtf(var + 1e-5f);
        float4 o4;
        o4.x = (yv.x - mu) * rs * g4.x + bb4.x;
        o4.y = (yv.y - mu) * rs * g4.y + bb4.y;
        o4.z = (yv.z - mu) * rs * g4.z + bb4.z;
        o4.w = (yv.w - mu) * rs * g4.w + bb4.w;
        *(float4*)&out[(size_t)row * 256 + cg * 4] = o4;
    }
}

extern "C" void kernel_launch(void* const* d_in, const int* in_sizes, int n_in,
                              void* d_out, int out_size, void* d_ws, size_t ws_size,
                              hipStream_t stream)
{
    (void)in_sizes; (void)n_in; (void)out_size; (void)ws_size;
    const float* x      = (const float*)d_in[0];
    const float* bulk   = (const float*)d_in[1];
    const float* Wq     = (const float*)d_in[2];
    const float* bq     = (const float*)d_in[3];
    const float* Wk     = (const float*)d_in[4];
    const float* bk     = (const float*)d_in[5];
    const float* Wv     = (const float*)d_in[6];
    const float* bv     = (const float*)d_in[7];
    const float* Wo     = (const float*)d_in[8];
    const float* bo     = (const float*)d_in[9];
    const float* conv_w = (const float*)d_in[10];
    const float* conv_b = (const float*)d_in[11];
    const float* gate_w = (const float*)d_in[12];
    const float* gate_b = (const float*)d_in[13];
    const float* ln_g   = (const float*)d_in[14];
    const float* ln_b   = (const float*)d_in[15];
    float* out = (float*)d_out;

    char* ws = (char*)d_ws;
    float* WqT = (float*)ws;            // 256 KB
    float* WkT = WqT + 65536;
    float* WvT = WqT + 131072;
    float* WoT = WqT + 196608;          // ends at 1 MB
    unsigned short* qws = (unsigned short*)(ws + (1u << 20));   // 4 MB bf16
    unsigned short* kws = qws + 2097152;                        // 4 MB
    unsigned short* vws = qws + 4194304;                        // 4 MB
    float* og = (float*)(ws + 13u * (1u << 20));                // 8 MB f32
    unsigned short* vTw = (unsigned short*)(ws + 21u * (1u << 20)); // 4 MB bf16 (total 25 MB)

    transpose_w<<<dim3(8, 4), 256, 0, stream>>>(Wq, Wk, Wv, Wo, WqT, WkT, WvT, WoT);
    qkv_proj<<<dim3(512, 3), 256, 0, stream>>>(x, WqT, WkT, WvT, bq, bk, bv, qws, kws, vws);
    transpose_v<<<dim3(4, 64), 256, 0, stream>>>(vws, vTw);
    attn_mfma<<<dim3(16, 16), 512, 0, stream>>>(qws, kws, vTw, bulk, conv_w, conv_b,
                                                gate_w, gate_b, og);
    proj_ln<<<512, 256, 0, stream>>>(og, x, WoT, bo, ln_g, ln_b, out);
}

// Round 3
// 135.169 us; speedup vs baseline: 2.2550x; 1.1469x over previous
//
#include <hip/hip_runtime.h>
#include <hip/hip_bf16.h>

#define C_ 256
#define H_ 8
#define DH_ 32
#define L_ 1024

typedef __bf16 bf16x8_t __attribute__((ext_vector_type(8)));
typedef float f32x4_t __attribute__((ext_vector_type(4)));

union V16 {
    uint4 u4;
    bf16x8_t b8;
    f32x4_t f4;
    unsigned u[4];
};

__device__ __forceinline__ unsigned cvt_pk(float lo, float hi) {
    unsigned r;
    asm volatile("v_cvt_pk_bf16_f32 %0, %1, %2" : "=v"(r) : "v"(lo), "v"(hi));
    return r;
}

__device__ __forceinline__ f32x4_t mfma16(bf16x8_t a, bf16x8_t b, f32x4_t c) {
    return __builtin_amdgcn_mfma_f32_16x16x32_bf16(a, b, c, 0, 0, 0);
}

__device__ __forceinline__ unsigned short f2bf(float f) {
    unsigned u = __float_as_uint(f);
    u += 0x7fffu + ((u >> 16) & 1u);
    return (unsigned short)(u >> 16);
}

__device__ __forceinline__ float bfup(unsigned short u) {
    return __uint_as_float((unsigned)u << 16);
}

// ---------------- K0: convert x, bulk, weights -> bf16 ----------------
// grid (2048, 6), block 256. y: 0=x, 1=bulk, 2..5=Wq/Wk/Wv/Wo.
__global__ __launch_bounds__(256) void conv_bf16(
    const float* __restrict__ x, const float* __restrict__ bulk,
    const float* __restrict__ Wq, const float* __restrict__ Wk,
    const float* __restrict__ Wv, const float* __restrict__ Wo,
    unsigned short* __restrict__ xb, unsigned short* __restrict__ bulkb,
    unsigned short* __restrict__ wb)
{
    int ysel = blockIdx.y;
    const float* src; unsigned short* dst; int n4;
    if (ysel == 0)      { src = x;    dst = xb;    n4 = 524288; }
    else if (ysel == 1) { src = bulk; dst = bulkb; n4 = 524288; }
    else {
        src = (ysel == 2) ? Wq : (ysel == 3) ? Wk : (ysel == 4) ? Wv : Wo;
        dst = wb + (ysel - 2) * 65536; n4 = 16384;
    }
    int i = blockIdx.x * 256 + threadIdx.x;
    if (i >= n4) return;
    float4 v = ((const float4*)src)[i];
    ushort4 o;
    o.x = f2bf(v.x); o.y = f2bf(v.y); o.z = f2bf(v.z); o.w = f2bf(v.w);
    ((ushort4*)dst)[i] = o;
}

// ---------------- K1: QKV projection via MFMA ----------------
// grid (128, 12), block 256 = 4 waves (2m x 2n), wave = 32m x 32n, K=256.
__global__ __launch_bounds__(256) void qkv_mfma(
    const unsigned short* __restrict__ xb, const unsigned short* __restrict__ wb,
    const float* __restrict__ bq, const float* __restrict__ bk, const float* __restrict__ bv,
    unsigned short* __restrict__ qws, unsigned short* __restrict__ kws,
    unsigned short* __restrict__ vws)
{
    const int t = threadIdx.x;
    const int lane = t & 63, w = t >> 6;
    const int r = lane & 15, g = lane >> 4;
    const int m0 = blockIdx.x * 64 + (w >> 1) * 32;
    const int n0g = blockIdx.y * 64 + (w & 1) * 32;
    const int z = n0g >> 8, nl = n0g & 255;

    const uint4* ap = (const uint4*)xb;
    const uint4* bp = (const uint4*)(wb + z * 65536);

    f32x4_t acc[2][2] = {};
#pragma unroll
    for (int kt = 0; kt < 8; ++kt) {
        V16 a0, a1, b0, b1;
        a0.u4 = ap[(m0 + r) * 32 + kt * 4 + g];
        a1.u4 = ap[(m0 + 16 + r) * 32 + kt * 4 + g];
        b0.u4 = bp[(nl + r) * 32 + kt * 4 + g];
        b1.u4 = bp[(nl + 16 + r) * 32 + kt * 4 + g];
        acc[0][0] = mfma16(a0.b8, b0.b8, acc[0][0]);
        acc[0][1] = mfma16(a0.b8, b1.b8, acc[0][1]);
        acc[1][0] = mfma16(a1.b8, b0.b8, acc[1][0]);
        acc[1][1] = mfma16(a1.b8, b1.b8, acc[1][1]);
    }

    const float* bias = (z == 0) ? bq : (z == 1) ? bk : bv;
    unsigned short* dst = (z == 0) ? qws : (z == 1) ? kws : vws;
    const float sc = (z == 0) ? 0.17677669529663687f : 1.0f;
    float bv0 = bias[nl + r], bv1 = bias[nl + 16 + r];
#pragma unroll
    for (int mi = 0; mi < 2; ++mi)
#pragma unroll
        for (int ni = 0; ni < 2; ++ni) {
            int n = nl + ni * 16 + r;
            int h = n >> 5, d = n & 31;
            float bb = ni ? bv1 : bv0;
#pragma unroll
            for (int e = 0; e < 4; ++e) {
                int m = m0 + mi * 16 + g * 4 + e;
                int bs = m >> 10, l = m & 1023;
                float val = (acc[mi][ni][e] + bb) * sc;
                dst[((size_t)((bs * H_ + h) * L_ + l)) * DH_ + d] = f2bf(val);
            }
        }
}

// ---------------- K1b: transpose V per head: [hb][l][d] -> [hb][d][l] ----------------
__global__ __launch_bounds__(256) void transpose_v(const unsigned short* __restrict__ vws,
                                                   unsigned short* __restrict__ vT)
{
    __shared__ unsigned short tile[32][264];
    int hb = blockIdx.y;
    int l0 = blockIdx.x * 256;
    int t = threadIdx.x;
    const unsigned* src = (const unsigned*)(vws + (size_t)hb * 32768) + l0 * 16;
    for (int i = t; i < 4096; i += 256) {
        int l = i >> 4, d2 = i & 15;
        unsigned u = src[i];
        tile[d2 * 2][l]     = (unsigned short)(u & 0xffffu);
        tile[d2 * 2 + 1][l] = (unsigned short)(u >> 16);
    }
    __syncthreads();
    unsigned* dst = (unsigned*)(vT + (size_t)hb * 32768);
    int d = t >> 3, seg = (t & 7) * 32;
#pragma unroll
    for (int j = 0; j < 16; ++j) {
        int l = seg + j * 2;
        unsigned u = (unsigned)tile[d][l] | ((unsigned)tile[d][l + 1] << 16);
        dst[d * 512 + (l0 + l) / 2] = u;
    }
}

// ---------------- K2: MFMA flash attention + fused gate ----------------
// grid (32, 16), block 512 = 8 waves = 4 tracks x 2 q-halves; wave = 16 q rows.
#define LOADK(DST, KV)                                                         \
    {                                                                          \
        _Pragma("unroll") for (int m_ = 0; m_ < 4; ++m_) {                     \
            V16 tmp_; tmp_.u4 = kp[((KV) + m_ * 16 + r) * 4 + g];              \
            DST[m_] = tmp_.b8;                                                 \
        }                                                                      \
    }
#define LOADB(DST, KV)                                                         \
    {                                                                          \
        _Pragma("unroll") for (int m_ = 0; m_ < 4; ++m_)                       \
            DST[m_] = bp4[(q0 + r) * 256 + (((KV) + m_ * 16) >> 2) + g];       \
    }

__global__ __launch_bounds__(512, 4) void attn_mfma(
    const unsigned short* __restrict__ qws, const unsigned short* __restrict__ kws,
    const unsigned short* __restrict__ vT, const unsigned short* __restrict__ bulkb,
    const float* __restrict__ conv_w, const float* __restrict__ conv_b,
    const float* __restrict__ gate_w, const float* __restrict__ gate_b,
    unsigned short* __restrict__ ogb)
{
    const int t = threadIdx.x;
    const int lane = t & 63, w = t >> 6;
    const int g = lane >> 4, r = lane & 15;
    const int s = w & 3, qh = w >> 2;
    const int h = blockIdx.y & 7, b = blockIdx.y >> 3;
    const int hb = (b * 4 + s) * 8 + h;
    const int q0 = blockIdx.x * 32 + qh * 16;

    const uint4* kp = (const uint4*)(kws + (size_t)hb * 32768);
    const uint4* qp = (const uint4*)(qws + (size_t)hb * 32768);
    const uint4* vp = (const uint4*)(vT  + (size_t)hb * 32768);
    const ushort4* bp4 = (const ushort4*)(bulkb + (size_t)b * 1048576);
    const float cw = conv_w[h], cb = conv_b[h];

    // Q B-frag: lane holds Q[q0+r][g*8 .. g*8+7]
    bf16x8_t qb;
    { V16 tmp; tmp.u4 = qp[(q0 + r) * 4 + g]; qb = tmp.b8; }

    f32x4_t o[2] = {};              // O^T: row d = md*16+g*4+e, col q = r
    float mst = -3.0e38f, lst = 0.f;

    bf16x8_t KA[4], KB[4];
    ushort4 BA[4], BB[4];
    LOADK(KA, 0)
    LOADB(BA, 0)

#define PHASE(KC, BC, KV0, KN, BN, KVN)                                        \
    {                                                                          \
        const int kv0_ = (KV0);                                                \
        uint4 vau[4];                                                          \
        _Pragma("unroll") for (int md_ = 0; md_ < 2; ++md_)                    \
        _Pragma("unroll") for (int s2_ = 0; s2_ < 2; ++s2_)                    \
            vau[md_ * 2 + s2_] = vp[(md_ * 16 + r) * 128 + (kv0_ >> 3) + s2_ * 4 + g]; \
        LOADK(KN, (KVN))                                                       \
        LOADB(BN, (KVN))                                                       \
        f32x4_t acc[4];                                                        \
        _Pragma("unroll") for (int m_ = 0; m_ < 4; ++m_) {                     \
            f32x4_t b4_;                                                       \
            b4_[0] = bfup(BC[m_].x); b4_[1] = bfup(BC[m_].y);                  \
            b4_[2] = bfup(BC[m_].z); b4_[3] = bfup(BC[m_].w);                  \
            acc[m_] = cw * b4_ + cb;                                           \
        }                                                                      \
        __builtin_amdgcn_s_setprio(1);                                         \
        _Pragma("unroll") for (int m_ = 0; m_ < 4; ++m_)                       \
            acc[m_] = mfma16(KC[m_], qb, acc[m_]);                             \
        __builtin_amdgcn_s_setprio(0);                                         \
        float pmax = acc[0][0];                                                \
        _Pragma("unroll") for (int m_ = 0; m_ < 4; ++m_)                       \
        _Pragma("unroll") for (int e_ = 0; e_ < 4; ++e_)                       \
            pmax = fmaxf(pmax, acc[m_][e_]);                                   \
        pmax = fmaxf(pmax, __shfl_xor(pmax, 16, 64));                          \
        pmax = fmaxf(pmax, __shfl_xor(pmax, 32, 64));                          \
        if (!__all(pmax <= mst + 8.0f)) {                                      \
            float mnew = fmaxf(mst, pmax);                                     \
            float scale = __expf(mst - mnew);                                  \
            mst = mnew; lst *= scale;                                          \
            o[0] *= scale; o[1] *= scale;                                      \
        }                                                                      \
        float psum = 0.f;                                                      \
        _Pragma("unroll") for (int m_ = 0; m_ < 4; ++m_)                       \
        _Pragma("unroll") for (int e_ = 0; e_ < 4; ++e_) {                     \
            float p_ = __expf(acc[m_][e_] - mst);                              \
            acc[m_][e_] = p_; psum += p_;                                      \
        }                                                                      \
        psum += __shfl_xor(psum, 16, 64);                                      \
        psum += __shfl_xor(psum, 32, 64);                                      \
        lst += psum;                                                           \
        unsigned pk[4][2];                                                     \
        _Pragma("unroll") for (int m_ = 0; m_ < 4; ++m_) {                     \
            pk[m_][0] = cvt_pk(acc[m_][0], acc[m_][1]);                        \
            pk[m_][1] = cvt_pk(acc[m_][2], acc[m_][3]);                        \
        }                                                                      \
        _Pragma("unroll") for (int s2_ = 0; s2_ < 2; ++s2_) {                  \
            V16 pb;                                                            \
            _Pragma("unroll") for (int u_ = 0; u_ < 4; ++u_) {                 \
                int srcl_ = ((2 * (g & 1) + (u_ >> 1)) << 4) | r;              \
                unsigned lo_ = (unsigned)__shfl((int)pk[2 * s2_][u_ & 1], srcl_, 64);     \
                unsigned hi_ = (unsigned)__shfl((int)pk[2 * s2_ + 1][u_ & 1], srcl_, 64); \
                pb.u[u_] = (g >= 2) ? hi_ : lo_;                               \
            }                                                                  \
            V16 va0_; va0_.u4 = vau[0 * 2 + s2_];                              \
            V16 va1_; va1_.u4 = vau[1 * 2 + s2_];                              \
            __builtin_amdgcn_s_setprio(1);                                     \
            o[0] = mfma16(va0_.b8, pb.b8, o[0]);                               \
            o[1] = mfma16(va1_.b8, pb.b8, o[1]);                               \
            __builtin_amdgcn_s_setprio(0);                                     \
        }                                                                      \
    }

    for (int kt = 0; kt < 16; kt += 2) {
        PHASE(KA, BA, kt * 64, KB, BB, (kt + 1) * 64)
        int kv2 = (kt + 2 < 16) ? (kt + 2) * 64 : 0;
        PHASE(KB, BB, (kt + 1) * 64, KA, BA, kv2)
    }

    // ---- epilogue: normalize, fused gate, store og as bf16 ----
    float linv = 1.0f / lst;
    o[0] *= linv;
    o[1] *= linv;

    // gate_w A-frags + gate_b (loaded here to keep main-loop VGPR low)
    bf16x8_t ga[2]; f32x4_t gb4[2];
#pragma unroll
    for (int mc = 0; mc < 2; ++mc) {
        const float* gwp = gate_w + (size_t)(h * 32 + mc * 16 + r) * 32 + g * 8;
        f32x4_t w0 = *(const f32x4_t*)gwp;
        f32x4_t w1 = *(const f32x4_t*)(gwp + 4);
        V16 tmp;
        tmp.u[0] = cvt_pk(w0[0], w0[1]); tmp.u[1] = cvt_pk(w0[2], w0[3]);
        tmp.u[2] = cvt_pk(w1[0], w1[1]); tmp.u[3] = cvt_pk(w1[2], w1[3]);
        ga[mc] = tmp.b8;
        gb4[mc] = *(const f32x4_t*)(gate_b + h * 32 + mc * 16 + g * 4);
    }

    unsigned pkO[2][2];
#pragma unroll
    for (int md = 0; md < 2; ++md) {
        pkO[md][0] = cvt_pk(o[md][0], o[md][1]);
        pkO[md][1] = cvt_pk(o[md][2], o[md][3]);
    }
    V16 ob;
#pragma unroll
    for (int u = 0; u < 4; ++u) {
        int srcl = ((2 * (g & 1) + (u >> 1)) << 4) | r;
        unsigned lo = (unsigned)__shfl((int)pkO[0][u & 1], srcl, 64);
        unsigned hi = (unsigned)__shfl((int)pkO[1][u & 1], srcl, 64);
        ob.u[u] = (g >= 2) ? hi : lo;
    }
    f32x4_t zero = {0.f, 0.f, 0.f, 0.f};
    f32x4_t gacc0 = mfma16(ga[0], ob.b8, zero);
    f32x4_t gacc1 = mfma16(ga[1], ob.b8, zero);
#pragma unroll
    for (int e = 0; e < 4; ++e) {
        float s0 = 1.0f / (1.0f + __expf(-(gacc0[e] + gb4[0][e])));
        float s1 = 1.0f / (1.0f + __expf(-(gacc1[e] + gb4[1][e])));
        o[0][e] *= s0;
        o[1][e] *= s1;
    }
    unsigned* ogp = (unsigned*)ogb;
#pragma unroll
    for (int md = 0; md < 2; ++md) {
        uint2 st;
        st.x = cvt_pk(o[md][0], o[md][1]);
        st.y = cvt_pk(o[md][2], o[md][3]);
        *(uint2*)&ogp[((size_t)(hb * 1024 + q0 + r)) * 16 + md * 8 + g * 2] = st;
    }
}

// ---------------- K3: out-proj + residual + layernorm via MFMA ----------------
// grid 512, block 512 = 8 waves; block = 16m x 256n, wave = 16m x 32n.
__global__ __launch_bounds__(512) void proj_ln_mfma(
    const unsigned short* __restrict__ ogb, const float* __restrict__ x,
    const unsigned short* __restrict__ wob, const float* __restrict__ bo,
    const float* __restrict__ ln_g, const float* __restrict__ ln_b,
    float* __restrict__ out)
{
    __shared__ float s1l[8][16];
    __shared__ float s2l[8][16];
    const int t = threadIdx.x;
    const int lane = t & 63, w = t >> 6;
    const int r = lane & 15, g = lane >> 4;
    const int m0 = blockIdx.x * 16;
    const int bs = m0 >> 10, l0 = m0 & 1023;
    const int n0 = w * 32;

    const uint4* ap = (const uint4*)ogb;
    const uint4* bp = (const uint4*)wob;

    f32x4_t acc[2] = {};
#pragma unroll
    for (int kt = 0; kt < 8; ++kt) {
        V16 a0, b0, b1;
        a0.u4 = ap[((size_t)(bs * 8 + kt) * 1024 + l0 + r) * 4 + g];
        b0.u4 = bp[(n0 + r) * 32 + kt * 4 + g];
        b1.u4 = bp[(n0 + 16 + r) * 32 + kt * 4 + g];
        acc[0] = mfma16(a0.b8, b0.b8, acc[0]);
        acc[1] = mfma16(a0.b8, b1.b8, acc[1]);
    }

    float bo0 = bo[n0 + r], bo1 = bo[n0 + 16 + r];
#pragma unroll
    for (int e = 0; e < 4; ++e) {
        int m = m0 + g * 4 + e;
        acc[0][e] += bo0 + x[(size_t)m * 256 + n0 + r];
        acc[1][e] += bo1 + x[(size_t)m * 256 + n0 + 16 + r];
    }
    // per-lane partial row sums over this wave's 32 cols
#pragma unroll
    for (int e = 0; e < 4; ++e) {
        float sm = acc[0][e] + acc[1][e];
        float sq = acc[0][e] * acc[0][e] + acc[1][e] * acc[1][e];
        sm += __shfl_xor(sm, 1, 64); sq += __shfl_xor(sq, 1, 64);
        sm += __shfl_xor(sm, 2, 64); sq += __shfl_xor(sq, 2, 64);
        sm += __shfl_xor(sm, 4, 64); sq += __shfl_xor(sq, 4, 64);
        sm += __shfl_xor(sm, 8, 64); sq += __shfl_xor(sq, 8, 64);
        if (r == 0) { s1l[w][g * 4 + e] = sm; s2l[w][g * 4 + e] = sq; }
    }
    __syncthreads();

    float g0 = ln_g[n0 + r], g1 = ln_g[n0 + 16 + r];
    float b0 = ln_b[n0 + r], b1 = ln_b[n0 + 16 + r];
#pragma unroll
    for (int e = 0; e < 4; ++e) {
        int mloc = g * 4 + e;
        float sm = 0.f, sq = 0.f;
#pragma unroll
        for (int wv = 0; wv < 8; ++wv) { sm += s1l[wv][mloc]; sq += s2l[wv][mloc]; }
        float mu = sm * (1.0f / 256.0f);
        float var = sq * (1.0f / 256.0f) - mu * mu;
        float rs = rsqrtf(var + 1e-5f);
        int m = m0 + mloc;
        out[(size_t)m * 256 + n0 + r]      = (acc[0][e] - mu) * rs * g0 + b0;
        out[(size_t)m * 256 + n0 + 16 + r] = (acc[1][e] - mu) * rs * g1 + b1;
    }
}

extern "C" void kernel_launch(void* const* d_in, const int* in_sizes, int n_in,
                              void* d_out, int out_size, void* d_ws, size_t ws_size,
                              hipStream_t stream)
{
    (void)in_sizes; (void)n_in; (void)out_size; (void)ws_size;
    const float* x      = (const float*)d_in[0];
    const float* bulk   = (const float*)d_in[1];
    const float* Wq     = (const float*)d_in[2];
    const float* bq     = (const float*)d_in[3];
    const float* Wk     = (const float*)d_in[4];
    const float* bk     = (const float*)d_in[5];
    const float* Wv     = (const float*)d_in[6];
    const float* bv     = (const float*)d_in[7];
    const float* Wo     = (const float*)d_in[8];
    const float* bo     = (const float*)d_in[9];
    const float* conv_w = (const float*)d_in[10];
    const float* conv_b = (const float*)d_in[11];
    const float* gate_w = (const float*)d_in[12];
    const float* gate_b = (const float*)d_in[13];
    const float* ln_g   = (const float*)d_in[14];
    const float* ln_b   = (const float*)d_in[15];
    float* out = (float*)d_out;

    char* ws = (char*)d_ws;
    unsigned short* xb    = (unsigned short*)ws;                  // 4 MB
    unsigned short* bulkb = (unsigned short*)(ws + (4u << 20));   // 4 MB
    unsigned short* wb    = (unsigned short*)(ws + (8u << 20));   // 512 KB (4 x 256x256)
    unsigned short* qws   = (unsigned short*)(ws + (8u << 20) + (512u << 10)); // 4 MB
    unsigned short* kws   = qws + 2097152;                        // 4 MB
    unsigned short* vws   = qws + 4194304;                        // 4 MB
    unsigned short* vT    = qws + 6291456;                        // 4 MB
    unsigned short* ogb   = vws;  // alias: vws dead after transpose_v (stream-ordered)
    unsigned short* wob   = wb + 3 * 65536;

    conv_bf16<<<dim3(2048, 6), 256, 0, stream>>>(x, bulk, Wq, Wk, Wv, Wo, xb, bulkb, wb);
    qkv_mfma<<<dim3(128, 12), 256, 0, stream>>>(xb, wb, bq, bk, bv, qws, kws, vws);
    transpose_v<<<dim3(4, 64), 256, 0, stream>>>(vws, vT);
    attn_mfma<<<dim3(32, 16), 512, 0, stream>>>(qws, kws, vT, bulkb, conv_w, conv_b,
                                                gate_w, gate_b, ogb);
    proj_ln_mfma<<<512, 512, 0, stream>>>(ogb, x, wob, bo, ln_g, ln_b, out);
}